// Round 1
// baseline (462.019 us; speedup 1.0000x reference)
//
#include <hip/hip_runtime.h>
#include <hip/hip_bf16.h>

typedef unsigned int uint;
typedef unsigned short ushort;
typedef __bf16 bf16x8 __attribute__((ext_vector_type(8)));
typedef float f32x4 __attribute__((ext_vector_type(4)));
typedef unsigned short u16x2 __attribute__((ext_vector_type(2)));

#define T_TOK 1024
#define HDIM 2880
#define IDIM 2880
#define NEXP 8
#define GU 5760         // 2*IDIM
#define QK1 1440        // HDIM/2 bytes per gate_up row (stored as int32 each)
#define SG1 90          // HDIM/32
#define QK2 1440        // IDIM/2
#define SG2 90
#define MAXR 2048       // T_TOK * TOPK

#define LISTS_OFF 256
#define GATED_OFF (1u << 17)

// ---------- helpers ----------

static __device__ __forceinline__ uint pkadd16(uint a, uint b) {
  u16x2 x = __builtin_bit_cast(u16x2, a);
  u16x2 y = __builtin_bit_cast(u16x2, b);
  u16x2 r = x + y;                      // v_pk_add_u16
  return __builtin_bit_cast(uint, r);
}

// Decode 4 fp4-pair bytes (packed in P, one byte per input int32) into 4 dwords,
// each dword = two bf16 (low nibble -> even k first). sAdd2 = ((s-127)<<7) in both
// halves; added only where magnitude != 0 (exact power-of-two scaling in bf16).
static __device__ __forceinline__ void decode8(uint P, uint sAdd2, uint out[4]) {
  uint L  = P & 0x0F0F0F0Fu;
  uint Hh = (P >> 4) & 0x0F0F0F0Fu;
  uint Lm = L & 0x07070707u,  Hm = Hh & 0x07070707u;
  uint Lsg = (L & 0x08080808u) << 4, Hsg = (Hh & 0x08080808u) << 4;
  // bf16 of fp4 magnitudes {0,.5,1,1.5,2,3,4,6}: hi bytes, lo bytes
  uint hiL = __builtin_amdgcn_perm(0x40404040u, 0x3F3F3F00u, Lm) | Lsg;
  uint hiH = __builtin_amdgcn_perm(0x40404040u, 0x3F3F3F00u, Hm) | Hsg;
  uint loL = __builtin_amdgcn_perm(0xC0804000u, 0xC0800000u, Lm);
  uint loH = __builtin_amdgcn_perm(0xC0804000u, 0xC0800000u, Hm);
  uint mL  = __builtin_amdgcn_perm(0xFFFFFFFFu, 0xFFFFFF00u, Lm);  // 0xFF if mag!=0
  uint mH  = __builtin_amdgcn_perm(0xFFFFFFFFu, 0xFFFFFF00u, Hm);
  uint pL01 = __builtin_amdgcn_perm(hiL, loL, 0x05010400u);  // [lo0,hi0,lo1,hi1]
  uint pL23 = __builtin_amdgcn_perm(hiL, loL, 0x07030602u);
  uint pH01 = __builtin_amdgcn_perm(hiH, loH, 0x05010400u);
  uint pH23 = __builtin_amdgcn_perm(hiH, loH, 0x07030602u);
  uint aL01 = pkadd16(pL01, sAdd2 & __builtin_amdgcn_perm(mL, mL, 0x01010000u));
  uint aL23 = pkadd16(pL23, sAdd2 & __builtin_amdgcn_perm(mL, mL, 0x03030202u));
  uint aH01 = pkadd16(pH01, sAdd2 & __builtin_amdgcn_perm(mH, mH, 0x01010000u));
  uint aH23 = pkadd16(pH23, sAdd2 & __builtin_amdgcn_perm(mH, mH, 0x03030202u));
  out[0] = __builtin_amdgcn_perm(aH01, aL01, 0x05040100u);   // byte0: [k0,k1]
  out[1] = __builtin_amdgcn_perm(aH01, aL01, 0x07060302u);   // byte1
  out[2] = __builtin_amdgcn_perm(aH23, aL23, 0x05040100u);   // byte2
  out[3] = __builtin_amdgcn_perm(aH23, aL23, 0x07060302u);   // byte3
}

static __device__ __forceinline__ uint packbf2(float a, float b) {
  ushort ua = __builtin_bit_cast(ushort, __float2bfloat16(a));
  ushort ub = __builtin_bit_cast(ushort, __float2bfloat16(b));
  return (uint)ua | ((uint)ub << 16);
}

// ---------- kernel 0: per-expert routed-row lists ----------

__global__ void build_lists_kernel(const int* __restrict__ ridx,
                                   int* __restrict__ counts,
                                   int* __restrict__ lists) {
  int r = blockIdx.x * 256 + threadIdx.x;   // r = token*2 + slot
  if (r >= MAXR) return;
  int e = ridx[r];
  int pos = atomicAdd(&counts[e], 1);
  lists[e * MAXR + pos] = r;
}

// ---------- kernel 1: gate_up GEMM + activation -> gated (bf16) ----------
// grid: x = i-tile (45 of 64), y = m-tile (16 of 128 rows), z = expert

__global__ __launch_bounds__(256, 2)
void gemm1_kernel(const float* __restrict__ hidden,
                  const int* __restrict__ guq,    // [E][GU][QK1]
                  const int* __restrict__ gus,    // [E][GU][SG1]
                  const float* __restrict__ gub,  // [E][GU]
                  const int* __restrict__ counts,
                  const int* __restrict__ lists,
                  ushort* __restrict__ gated) {   // [MAXR][IDIM] bf16
  const int e = blockIdx.z;
  const int cnt = counts[e];
  const int mt = blockIdx.y;
  if (mt * 128 >= cnt) return;
  const int i0 = blockIdx.x * 64;
  const int tid = threadIdx.x;

  __shared__ ushort ldsA[128][72];
  __shared__ ushort ldsBg[64][72];
  __shared__ ushort ldsBu[64][72];
  __shared__ int rowid[128];

  if (tid < 128) {
    int rl = mt * 128 + tid;
    rowid[tid] = (rl < cnt) ? lists[e * MAXR + rl] : -1;
  }
  __syncthreads();

  // A staging coords: 128 rows x 2 halves (32 f32 each)
  const int arow = tid >> 1, ahalf = tid & 1;
  const int tokA = rowid[arow];
  const float* aptr = hidden + (size_t)(tokA >> 1) * HDIM + ahalf * 32;
  // B staging coords: 128 slab rows (j = 2*i0 + brr) x 2 halves (16 int32 each)
  const int brr = tid >> 1, bhalf = tid & 1;
  const size_t jrow = (size_t)e * GU + (size_t)(2 * i0 + brr);
  const int* bq = guq + jrow * QK1 + bhalf * 16;
  const int* bscale = gus + jrow * SG1 + bhalf;
  ushort* bdst = ((brr & 1) ? &ldsBu[brr >> 1][0] : &ldsBg[brr >> 1][0]) + bhalf * 32;

  f32x4 accg[8], accu[8];
  #pragma unroll
  for (int m = 0; m < 8; ++m) {
    accg[m] = (f32x4)0.f;
    accu[m] = (f32x4)0.f;
  }

  const int wv = tid >> 6, ln = tid & 63;
  const int ln15 = ln & 15, kq = ln >> 4;

  for (int k0 = 0; k0 < HDIM; k0 += 64) {
    // ---- stage A (f32 -> bf16) ----
    if (tokA >= 0) {
      const float4* s4 = (const float4*)(aptr + k0);
      #pragma unroll
      for (int c = 0; c < 4; ++c) {
        float4 f0 = s4[2 * c], f1 = s4[2 * c + 1];
        uint4 o;
        o.x = packbf2(f0.x, f0.y);
        o.y = packbf2(f0.z, f0.w);
        o.z = packbf2(f1.x, f1.y);
        o.w = packbf2(f1.z, f1.w);
        *(uint4*)&ldsA[arow][ahalf * 32 + c * 8] = o;
      }
    } else {
      uint4 z; z.x = z.y = z.z = z.w = 0u;
      #pragma unroll
      for (int c = 0; c < 4; ++c) *(uint4*)&ldsA[arow][ahalf * 32 + c * 8] = z;
    }
    // ---- stage B (fp4 -> bf16 with fused E8M0 scale) ----
    {
      int sv = bscale[k0 >> 5];
      uint sOff = ((uint)(sv - 127) << 7) & 0xFFFFu;
      uint sAdd2 = sOff | (sOff << 16);
      const int4* q4 = (const int4*)(bq + (k0 >> 1));
      #pragma unroll
      for (int c = 0; c < 4; ++c) {
        int4 v = q4[c];
        uint P = (uint)v.x | ((uint)v.y << 8) | ((uint)v.z << 16) | ((uint)v.w << 24);
        uint o[4];
        decode8(P, sAdd2, o);
        uint4 w4; w4.x = o[0]; w4.y = o[1]; w4.z = o[2]; w4.w = o[3];
        *(uint4*)(bdst + c * 8) = w4;
      }
    }
    __syncthreads();
    // ---- compute ----
    #pragma unroll
    for (int kk = 0; kk < 2; ++kk) {
      const int ko = kk * 32 + kq * 8;
      bf16x8 bg = *(const bf16x8*)&ldsBg[wv * 16 + ln15][ko];
      bf16x8 bu = *(const bf16x8*)&ldsBu[wv * 16 + ln15][ko];
      #pragma unroll
      for (int m = 0; m < 8; ++m) {
        bf16x8 av = *(const bf16x8*)&ldsA[m * 16 + ln15][ko];
        accg[m] = __builtin_amdgcn_mfma_f32_16x16x32_bf16(av, bg, accg[m], 0, 0, 0);
        accu[m] = __builtin_amdgcn_mfma_f32_16x16x32_bf16(av, bu, accu[m], 0, 0, 0);
      }
    }
    __syncthreads();
  }

  // ---- epilogue: bias + clamp + glu, write bf16 gated ----
  const int icol = i0 + wv * 16 + ln15;
  const float bgv = gub[(size_t)e * GU + 2 * icol];
  const float buv = gub[(size_t)e * GU + 2 * icol + 1];
  #pragma unroll
  for (int m = 0; m < 8; ++m) {
    #pragma unroll
    for (int rg = 0; rg < 4; ++rg) {
      int rl = m * 16 + kq * 4 + rg;
      int r = rowid[rl];
      if (r < 0) continue;
      float g = accg[m][rg] + bgv;
      float u = accu[m][rg] + buv;
      g = fminf(g, 7.f);
      u = fminf(fmaxf(u, -7.f), 7.f);
      float glu = g / (1.f + __expf(-1.702f * g));
      float val = (u + 1.f) * glu;
      gated[(size_t)r * IDIM + icol] =
          __builtin_bit_cast(ushort, __float2bfloat16(val));
    }
  }
}

// ---------- kernel 2: down GEMM + routed scatter-add ----------
// grid: x = h-tile (45 of 64), y = m-tile (16 of 128 rows), z = expert

__global__ __launch_bounds__(256, 2)
void gemm2_kernel(const ushort* __restrict__ gated,  // [MAXR][IDIM] bf16
                  const int* __restrict__ dq,        // [E][H][QK2]
                  const int* __restrict__ dsc,       // [E][H][SG2]
                  const float* __restrict__ dpb,     // [E][H]
                  const float* __restrict__ routing, // [MAXR]
                  const int* __restrict__ counts,
                  const int* __restrict__ lists,
                  float* __restrict__ outp) {        // [T][H]
  const int e = blockIdx.z;
  const int cnt = counts[e];
  const int mt = blockIdx.y;
  if (mt * 128 >= cnt) return;
  const int h0 = blockIdx.x * 64;
  const int tid = threadIdx.x;

  __shared__ ushort ldsA[128][72];
  __shared__ ushort ldsB[64][72];
  __shared__ int rowid[128];

  if (tid < 128) {
    int rl = mt * 128 + tid;
    rowid[tid] = (rl < cnt) ? lists[e * MAXR + rl] : -1;
  }
  __syncthreads();

  const int arow = tid >> 1, ahalf = tid & 1;       // 128 rows x 2 halves (32 bf16)
  const int tokr = rowid[arow];
  const ushort* aptr = gated + (size_t)tokr * IDIM + ahalf * 32;
  const int brow = tid >> 2, bq4 = tid & 3;         // 64 rows x 4 quarters (8 int32)
  const size_t hrow = (size_t)e * HDIM + (size_t)(h0 + brow);
  const int* bq = dq + hrow * QK2 + bq4 * 8;
  const int* bscale = dsc + hrow * SG2 + (bq4 >> 1);
  ushort* bdst = &ldsB[brow][bq4 * 16];

  f32x4 acc[8];
  #pragma unroll
  for (int m = 0; m < 8; ++m) acc[m] = (f32x4)0.f;

  const int wv = tid >> 6, ln = tid & 63;
  const int ln15 = ln & 15, kq = ln >> 4;

  for (int k0 = 0; k0 < IDIM; k0 += 64) {
    // ---- stage A (already bf16) ----
    if (tokr >= 0) {
      const uint4* s4 = (const uint4*)(aptr + k0);
      #pragma unroll
      for (int c = 0; c < 4; ++c)
        *(uint4*)&ldsA[arow][ahalf * 32 + c * 8] = s4[c];
    } else {
      uint4 z; z.x = z.y = z.z = z.w = 0u;
      #pragma unroll
      for (int c = 0; c < 4; ++c) *(uint4*)&ldsA[arow][ahalf * 32 + c * 8] = z;
    }
    // ---- stage B ----
    {
      int sv = bscale[k0 >> 5];
      uint sOff = ((uint)(sv - 127) << 7) & 0xFFFFu;
      uint sAdd2 = sOff | (sOff << 16);
      const int4* q4 = (const int4*)(bq + (k0 >> 1));
      #pragma unroll
      for (int c = 0; c < 2; ++c) {
        int4 v = q4[c];
        uint P = (uint)v.x | ((uint)v.y << 8) | ((uint)v.z << 16) | ((uint)v.w << 24);
        uint o[4];
        decode8(P, sAdd2, o);
        uint4 w4; w4.x = o[0]; w4.y = o[1]; w4.z = o[2]; w4.w = o[3];
        *(uint4*)(bdst + c * 8) = w4;
      }
    }
    __syncthreads();
    // ---- compute ----
    #pragma unroll
    for (int kk = 0; kk < 2; ++kk) {
      const int ko = kk * 32 + kq * 8;
      bf16x8 bb = *(const bf16x8*)&ldsB[wv * 16 + ln15][ko];
      #pragma unroll
      for (int m = 0; m < 8; ++m) {
        bf16x8 av = *(const bf16x8*)&ldsA[m * 16 + ln15][ko];
        acc[m] = __builtin_amdgcn_mfma_f32_16x16x32_bf16(av, bb, acc[m], 0, 0, 0);
      }
    }
    __syncthreads();
  }

  // ---- epilogue: bias, routing weight, scatter-add ----
  const int hcol = h0 + wv * 16 + ln15;
  const float bv = dpb[(size_t)e * HDIM + hcol];
  #pragma unroll
  for (int m = 0; m < 8; ++m) {
    #pragma unroll
    for (int rg = 0; rg < 4; ++rg) {
      int rl = m * 16 + kq * 4 + rg;
      int r = rowid[rl];
      if (r < 0) continue;
      float wgt = routing[r];
      atomicAdd(outp + (size_t)(r >> 1) * HDIM + hcol, wgt * (acc[m][rg] + bv));
    }
  }
}

// ---------- launch ----------

extern "C" void kernel_launch(void* const* d_in, const int* in_sizes, int n_in,
                              void* d_out, int out_size, void* d_ws, size_t ws_size,
                              hipStream_t stream) {
  const float* hidden  = (const float*)d_in[0];
  const float* routing = (const float*)d_in[1];
  const float* gub     = (const float*)d_in[2];
  const float* dpb     = (const float*)d_in[3];
  const int*   ridx    = (const int*)d_in[4];
  const int*   guq     = (const int*)d_in[5];
  const int*   gus     = (const int*)d_in[6];
  const int*   dq      = (const int*)d_in[7];
  const int*   dsc     = (const int*)d_in[8];
  float* outp = (float*)d_out;

  char* ws = (char*)d_ws;
  int* counts = (int*)ws;
  int* lists  = (int*)(ws + LISTS_OFF);
  ushort* gated = (ushort*)(ws + GATED_OFF);

  hipMemsetAsync(counts, 0, LISTS_OFF, stream);
  hipMemsetAsync(d_out, 0, (size_t)T_TOK * HDIM * sizeof(float), stream);

  build_lists_kernel<<<MAXR / 256, 256, 0, stream>>>(ridx, counts, lists);

  dim3 grid1(IDIM / 64, MAXR / 128, NEXP);
  gemm1_kernel<<<grid1, 256, 0, stream>>>(hidden, guq, gus, gub, counts, lists, gated);

  dim3 grid2(HDIM / 64, MAXR / 128, NEXP);
  gemm2_kernel<<<grid2, 256, 0, stream>>>(gated, dq, dsc, dpb, routing,
                                          counts, lists, outp);
}

// Round 2
// 262.608 us; speedup vs baseline: 1.7594x; 1.7594x over previous
//
#include <hip/hip_runtime.h>
#include <hip/hip_bf16.h>

typedef unsigned int uint;
typedef unsigned short ushort;
typedef __bf16 bf16x8 __attribute__((ext_vector_type(8)));
typedef float f32x4 __attribute__((ext_vector_type(4)));
typedef unsigned short u16x2 __attribute__((ext_vector_type(2)));

#define T_TOK 1024
#define HDIM 2880
#define IDIM 2880
#define NEXP 8
#define GU 5760
#define QK1 1440        // HDIM/2 int32 per gate_up row
#define SG1 90
#define QK2 1440
#define SG2 90
#define MAXR 2048
#define NK 45           // K-steps of 64 over 2880

#define BM 384          // rows per m-tile (covers cnt ~256+slack in ONE tile)
#define BGU 192         // gu-rows per gemm1 block (96 i-cols)
#define BNH 64          // h-cols per gemm2 block

#define LDA 72          // padded LDS row stride (ushort)

#define LISTS_OFF 256
#define HB_OFF (1u << 17)
#define GATED_OFF_PRE 6029312u                      // HB_OFF + 1024*2880*2
#define GATED_OFF_RAW (1u << 17)
#define WS_NEED (GATED_OFF_PRE + (size_t)MAXR * IDIM * 2)   // ~17.8 MB

// ---------- helpers ----------

static __device__ __forceinline__ uint pkadd16(uint a, uint b) {
  u16x2 x = __builtin_bit_cast(u16x2, a);
  u16x2 y = __builtin_bit_cast(u16x2, b);
  u16x2 r = x + y;
  return __builtin_bit_cast(uint, r);
}

// Decode 4 fp4-pair bytes (one byte per int32, packed into P) into 4 dwords of
// 2×bf16 (low nibble = even k first), with E8M0 scale fused as exponent add.
static __device__ __forceinline__ void decode8(uint P, uint sAdd2, uint out[4]) {
  uint L  = P & 0x0F0F0F0Fu;
  uint Hh = (P >> 4) & 0x0F0F0F0Fu;
  uint Lm = L & 0x07070707u,  Hm = Hh & 0x07070707u;
  uint Lsg = (L & 0x08080808u) << 4, Hsg = (Hh & 0x08080808u) << 4;
  uint hiL = __builtin_amdgcn_perm(0x40404040u, 0x3F3F3F00u, Lm) | Lsg;
  uint hiH = __builtin_amdgcn_perm(0x40404040u, 0x3F3F3F00u, Hm) | Hsg;
  uint loL = __builtin_amdgcn_perm(0xC0804000u, 0xC0800000u, Lm);
  uint loH = __builtin_amdgcn_perm(0xC0804000u, 0xC0800000u, Hm);
  uint mL  = __builtin_amdgcn_perm(0xFFFFFFFFu, 0xFFFFFF00u, Lm);
  uint mH  = __builtin_amdgcn_perm(0xFFFFFFFFu, 0xFFFFFF00u, Hm);
  uint pL01 = __builtin_amdgcn_perm(hiL, loL, 0x05010400u);
  uint pL23 = __builtin_amdgcn_perm(hiL, loL, 0x07030602u);
  uint pH01 = __builtin_amdgcn_perm(hiH, loH, 0x05010400u);
  uint pH23 = __builtin_amdgcn_perm(hiH, loH, 0x07030602u);
  uint aL01 = pkadd16(pL01, sAdd2 & __builtin_amdgcn_perm(mL, mL, 0x01010000u));
  uint aL23 = pkadd16(pL23, sAdd2 & __builtin_amdgcn_perm(mL, mL, 0x03030202u));
  uint aH01 = pkadd16(pH01, sAdd2 & __builtin_amdgcn_perm(mH, mH, 0x01010000u));
  uint aH23 = pkadd16(pH23, sAdd2 & __builtin_amdgcn_perm(mH, mH, 0x03030202u));
  out[0] = __builtin_amdgcn_perm(aH01, aL01, 0x05040100u);
  out[1] = __builtin_amdgcn_perm(aH01, aL01, 0x07060302u);
  out[2] = __builtin_amdgcn_perm(aH23, aL23, 0x05040100u);
  out[3] = __builtin_amdgcn_perm(aH23, aL23, 0x07060302u);
}

static __device__ __forceinline__ uint packbf2(float a, float b) {
  ushort ua = __builtin_bit_cast(ushort, __float2bfloat16(a));
  ushort ub = __builtin_bit_cast(ushort, __float2bfloat16(b));
  return (uint)ua | ((uint)ub << 16);
}

// ---------- kernel 0: routed-row lists ----------

__global__ void build_lists_kernel(const int* __restrict__ ridx,
                                   int* __restrict__ counts,
                                   int* __restrict__ lists) {
  int r = blockIdx.x * 256 + threadIdx.x;
  if (r >= MAXR) return;
  int e = ridx[r];
  int pos = atomicAdd(&counts[e], 1);
  lists[e * MAXR + pos] = r;
}

// ---------- kernel 0b: hidden f32 -> bf16 ----------

__global__ void cvt_kernel(const float* __restrict__ in, ushort* __restrict__ out) {
  int i = (blockIdx.x * 256 + threadIdx.x) * 8;
  float4 a = *(const float4*)(in + i);
  float4 b = *(const float4*)(in + i + 4);
  uint4 o;
  o.x = packbf2(a.x, a.y); o.y = packbf2(a.z, a.w);
  o.z = packbf2(b.x, b.y); o.w = packbf2(b.z, b.w);
  *(uint4*)(out + i) = o;
}

// ---------- kernel 1: gate_up GEMM + activation -> gated ----------
// 512 thr, BM=384 rows, BGU=192 gu-rows, BK=64, depth-1 reg prefetch.

template <bool PRE>
__global__ __launch_bounds__(512, 2)
void gemm1_kernel(const float* __restrict__ hiddenF,
                  const ushort* __restrict__ hiddenB,
                  const int* __restrict__ guq,
                  const int* __restrict__ gus,
                  const float* __restrict__ gub,
                  const int* __restrict__ counts,
                  const int* __restrict__ lists,
                  ushort* __restrict__ gated) {
  const int e = blockIdx.z;
  const int cnt = counts[e];
  const int mt = blockIdx.y;
  if (mt * BM >= cnt) return;
  const int gu0 = blockIdx.x * BGU;
  const int tid = threadIdx.x;

  extern __shared__ char smem[];
  ushort* lA = (ushort*)smem;                  // [BM][LDA]
  ushort* lB = lA + BM * LDA;                  // [BGU][LDA]
  int* rowid = (int*)(lB + BGU * LDA);         // [BM]

  for (int i = tid; i < BM; i += 512) {
    int rl = mt * BM + i;
    rowid[i] = (rl < cnt) ? lists[e * MAXR + rl] : -1;
  }
  __syncthreads();

  const int srow = tid >> 3;     // 0..63
  const int soff = tid & 7;      // 16B chunk -> k-offset soff*8

  // A staging: rows srow+64j, j=0..5
  uint avalid = 0;
  const ushort* aB[6];
  const float*  aF[6];
  #pragma unroll
  for (int j = 0; j < 6; ++j) {
    int r = rowid[srow + 64 * j];
    if (r >= 0) avalid |= (1u << j);
    int tok = (r >= 0) ? (r >> 1) : 0;
    if (PRE) aB[j] = hiddenB + (size_t)tok * HDIM + soff * 8;
    else     aF[j] = hiddenF + (size_t)tok * HDIM + soff * 8;
  }
  // B staging: rows srow+64j, j=0..2 (base ptrs; j-offset folded as immediate)
  const size_t jrow0 = (size_t)e * GU + gu0 + srow;
  const int* bq0 = guq + jrow0 * QK1 + soff * 4;
  const int* bs0 = gus + jrow0 * SG1 + (soff >> 2);

  f32x4 acc[6][6];
  #pragma unroll
  for (int m = 0; m < 6; ++m)
    #pragma unroll
    for (int n = 0; n < 6; ++n) acc[m][n] = (f32x4)0.f;

  const int ln = tid & 63;
  const int ln15 = ln & 15, kq = ln >> 4;
  const int wv = tid >> 6, wm = wv & 3, wn = wv >> 2;

  uint4 aP[6];
  int4  bP[3];
  int   sP[3];

  auto load_step = [&](int k0) {
    #pragma unroll
    for (int j = 0; j < 6; ++j) {
      if (avalid & (1u << j)) {
        if (PRE) {
          aP[j] = *(const uint4*)(aB[j] + k0);
        } else {
          float4 f0 = *(const float4*)(aF[j] + k0);
          float4 f1 = *(const float4*)(aF[j] + k0 + 4);
          aP[j].x = packbf2(f0.x, f0.y); aP[j].y = packbf2(f0.z, f0.w);
          aP[j].z = packbf2(f1.x, f1.y); aP[j].w = packbf2(f1.z, f1.w);
        }
      } else {
        aP[j].x = aP[j].y = aP[j].z = aP[j].w = 0u;
      }
    }
    #pragma unroll
    for (int j = 0; j < 3; ++j) {
      bP[j] = *(const int4*)(bq0 + (size_t)j * 64 * QK1 + (k0 >> 1));
      sP[j] = *(bs0 + (size_t)j * 64 * SG1 + (k0 >> 5));
    }
  };

  load_step(0);

  for (int ks = 0; ks < NK; ++ks) {
    #pragma unroll
    for (int j = 0; j < 6; ++j)
      *(uint4*)&lA[(srow + 64 * j) * LDA + soff * 8] = aP[j];
    #pragma unroll
    for (int j = 0; j < 3; ++j) {
      uint P = (uint)bP[j].x | ((uint)bP[j].y << 8) |
               ((uint)bP[j].z << 16) | ((uint)bP[j].w << 24);
      uint sOff = ((uint)(sP[j] - 127) << 7) & 0xFFFFu;
      uint sAdd2 = sOff | (sOff << 16);
      uint o[4];
      decode8(P, sAdd2, o);
      uint4 w; w.x = o[0]; w.y = o[1]; w.z = o[2]; w.w = o[3];
      *(uint4*)&lB[(srow + 64 * j) * LDA + soff * 8] = w;
    }
    __syncthreads();
    if (ks + 1 < NK) load_step((ks + 1) * 64);   // overlap with MFMA phase
    #pragma unroll
    for (int kf = 0; kf < 2; ++kf) {
      const int ko = kf * 32 + kq * 8;
      bf16x8 bfr[6];
      #pragma unroll
      for (int n = 0; n < 6; ++n)
        bfr[n] = *(const bf16x8*)&lB[(wn * 96 + n * 16 + ln15) * LDA + ko];
      #pragma unroll
      for (int m = 0; m < 6; ++m) {
        bf16x8 af = *(const bf16x8*)&lA[(wm * 96 + m * 16 + ln15) * LDA + ko];
        #pragma unroll
        for (int n = 0; n < 6; ++n)
          acc[m][n] = __builtin_amdgcn_mfma_f32_16x16x32_bf16(af, bfr[n], acc[m][n], 0, 0, 0);
      }
    }
    __syncthreads();
  }

  // epilogue: bias, pair g/u via shfl_xor(1) (gu parity == lane parity), glu
  float bias[6];
  #pragma unroll
  for (int n = 0; n < 6; ++n)
    bias[n] = gub[(size_t)e * GU + gu0 + wn * 96 + n * 16 + ln15];
  #pragma unroll
  for (int m = 0; m < 6; ++m) {
    #pragma unroll
    for (int rg = 0; rg < 4; ++rg) {
      int rl = wm * 96 + m * 16 + kq * 4 + rg;
      int r = rowid[rl];
      #pragma unroll
      for (int n = 0; n < 6; ++n) {
        float x = acc[m][n][rg] + bias[n];
        float y = __shfl_xor(x, 1);
        if (r >= 0 && !(ln & 1)) {
          float g = fminf(x, 7.f);
          float u = fminf(fmaxf(y, -7.f), 7.f);
          float glu = g / (1.f + __expf(-1.702f * g));
          float val = (u + 1.f) * glu;
          int gucol = gu0 + wn * 96 + n * 16 + ln15;
          gated[(size_t)r * IDIM + (gucol >> 1)] =
              __builtin_bit_cast(ushort, __float2bfloat16(val));
        }
      }
    }
  }
}

// ---------- kernel 2: down GEMM + routed scatter-add ----------
// 512 thr, BM=384 rows, BNH=64 h-cols, BK=64, depth-1 reg prefetch.

__global__ __launch_bounds__(512, 2)
void gemm2_kernel(const ushort* __restrict__ gated,
                  const int* __restrict__ dq,
                  const int* __restrict__ dsc,
                  const float* __restrict__ dpb,
                  const float* __restrict__ routing,
                  const int* __restrict__ counts,
                  const int* __restrict__ lists,
                  float* __restrict__ outp) {
  const int e = blockIdx.z;
  const int cnt = counts[e];
  const int mt = blockIdx.y;
  if (mt * BM >= cnt) return;
  const int h0 = blockIdx.x * BNH;
  const int tid = threadIdx.x;

  extern __shared__ char smem[];
  ushort* lA = (ushort*)smem;                  // [BM][LDA]
  ushort* lB = lA + BM * LDA;                  // [BNH][LDA]
  int* rowid = (int*)(lB + BNH * LDA);         // [BM]

  for (int i = tid; i < BM; i += 512) {
    int rl = mt * BM + i;
    rowid[i] = (rl < cnt) ? lists[e * MAXR + rl] : -1;
  }
  __syncthreads();

  const int srow = tid >> 3;
  const int soff = tid & 7;

  uint avalid = 0;
  const ushort* aB[6];
  #pragma unroll
  for (int j = 0; j < 6; ++j) {
    int r = rowid[srow + 64 * j];
    if (r >= 0) avalid |= (1u << j);
    int rr = (r >= 0) ? r : 0;
    aB[j] = gated + (size_t)rr * IDIM + soff * 8;
  }
  const size_t hrow = (size_t)e * HDIM + h0 + srow;
  const int* bq0 = dq + hrow * QK2 + soff * 4;
  const int* bs0 = dsc + hrow * SG2 + (soff >> 2);

  f32x4 acc[6][2];
  #pragma unroll
  for (int m = 0; m < 6; ++m) {
    acc[m][0] = (f32x4)0.f;
    acc[m][1] = (f32x4)0.f;
  }

  const int ln = tid & 63;
  const int ln15 = ln & 15, kq = ln >> 4;
  const int wv = tid >> 6, wm = wv & 3, wn = wv >> 2;

  uint4 aP[6];
  int4  bP;
  int   sP;

  auto load_step = [&](int k0) {
    #pragma unroll
    for (int j = 0; j < 6; ++j) {
      if (avalid & (1u << j)) aP[j] = *(const uint4*)(aB[j] + k0);
      else { aP[j].x = aP[j].y = aP[j].z = aP[j].w = 0u; }
    }
    bP = *(const int4*)(bq0 + (k0 >> 1));
    sP = *(bs0 + (k0 >> 5));
  };

  load_step(0);

  for (int ks = 0; ks < NK; ++ks) {
    #pragma unroll
    for (int j = 0; j < 6; ++j)
      *(uint4*)&lA[(srow + 64 * j) * LDA + soff * 8] = aP[j];
    {
      uint P = (uint)bP.x | ((uint)bP.y << 8) | ((uint)bP.z << 16) | ((uint)bP.w << 24);
      uint sOff = ((uint)(sP - 127) << 7) & 0xFFFFu;
      uint sAdd2 = sOff | (sOff << 16);
      uint o[4];
      decode8(P, sAdd2, o);
      uint4 w; w.x = o[0]; w.y = o[1]; w.z = o[2]; w.w = o[3];
      *(uint4*)&lB[srow * LDA + soff * 8] = w;
    }
    __syncthreads();
    if (ks + 1 < NK) load_step((ks + 1) * 64);
    #pragma unroll
    for (int kf = 0; kf < 2; ++kf) {
      const int ko = kf * 32 + kq * 8;
      bf16x8 bfr[2];
      #pragma unroll
      for (int n = 0; n < 2; ++n)
        bfr[n] = *(const bf16x8*)&lB[(wn * 32 + n * 16 + ln15) * LDA + ko];
      #pragma unroll
      for (int m = 0; m < 6; ++m) {
        bf16x8 af = *(const bf16x8*)&lA[(wm * 96 + m * 16 + ln15) * LDA + ko];
        #pragma unroll
        for (int n = 0; n < 2; ++n)
          acc[m][n] = __builtin_amdgcn_mfma_f32_16x16x32_bf16(af, bfr[n], acc[m][n], 0, 0, 0);
      }
    }
    __syncthreads();
  }

  float bias[2];
  #pragma unroll
  for (int n = 0; n < 2; ++n)
    bias[n] = dpb[(size_t)e * HDIM + h0 + wn * 32 + n * 16 + ln15];
  #pragma unroll
  for (int m = 0; m < 6; ++m) {
    #pragma unroll
    for (int rg = 0; rg < 4; ++rg) {
      int rl = wm * 96 + m * 16 + kq * 4 + rg;
      int r = rowid[rl];
      if (r < 0) continue;
      float wgt = routing[r];
      #pragma unroll
      for (int n = 0; n < 2; ++n) {
        int hcol = h0 + wn * 32 + n * 16 + ln15;
        atomicAdd(outp + (size_t)(r >> 1) * HDIM + hcol,
                  wgt * (acc[m][n][rg] + bias[n]));
      }
    }
  }
}

// ---------- launch ----------

extern "C" void kernel_launch(void* const* d_in, const int* in_sizes, int n_in,
                              void* d_out, int out_size, void* d_ws, size_t ws_size,
                              hipStream_t stream) {
  const float* hidden  = (const float*)d_in[0];
  const float* routing = (const float*)d_in[1];
  const float* gub     = (const float*)d_in[2];
  const float* dpb     = (const float*)d_in[3];
  const int*   ridx    = (const int*)d_in[4];
  const int*   guq     = (const int*)d_in[5];
  const int*   gus     = (const int*)d_in[6];
  const int*   dq      = (const int*)d_in[7];
  const int*   dsc     = (const int*)d_in[8];
  float* outp = (float*)d_out;

  char* ws = (char*)d_ws;
  int* counts = (int*)ws;
  int* lists  = (int*)(ws + LISTS_OFF);
  const bool pre = (ws_size >= WS_NEED);
  ushort* hb    = (ushort*)(ws + HB_OFF);
  ushort* gated = (ushort*)(ws + (pre ? GATED_OFF_PRE : GATED_OFF_RAW));

  const int LDS1 = (BM * LDA + BGU * LDA) * 2 + BM * 4;   // 84,480 B
  const int LDS2 = (BM * LDA + BNH * LDA) * 2 + BM * 4;   // 66,048 B
  if (pre)
    hipFuncSetAttribute((const void*)gemm1_kernel<true>,
                        hipFuncAttributeMaxDynamicSharedMemorySize, LDS1);
  else
    hipFuncSetAttribute((const void*)gemm1_kernel<false>,
                        hipFuncAttributeMaxDynamicSharedMemorySize, LDS1);
  hipFuncSetAttribute((const void*)gemm2_kernel,
                      hipFuncAttributeMaxDynamicSharedMemorySize, LDS2);

  hipMemsetAsync(counts, 0, 256, stream);
  hipMemsetAsync(d_out, 0, (size_t)out_size * sizeof(float), stream);

  build_lists_kernel<<<MAXR / 256, 256, 0, stream>>>(ridx, counts, lists);
  if (pre)
    cvt_kernel<<<(T_TOK * HDIM / 8) / 256, 256, 0, stream>>>(hidden, hb);

  dim3 grid1(GU / BGU, (MAXR + BM - 1) / BM, NEXP);
  if (pre)
    gemm1_kernel<true><<<grid1, 512, LDS1, stream>>>(hidden, hb, guq, gus, gub,
                                                     counts, lists, gated);
  else
    gemm1_kernel<false><<<grid1, 512, LDS1, stream>>>(hidden, hb, guq, gus, gub,
                                                      counts, lists, gated);

  dim3 grid2(HDIM / BNH, (MAXR + BM - 1) / BM, NEXP);
  gemm2_kernel<<<grid2, 512, LDS2, stream>>>(gated, dq, dsc, dpb, routing,
                                             counts, lists, outp);
}